// Round 2
// baseline (448.810 us; speedup 1.0000x reference)
//
#include <hip/hip_runtime.h>

// HierarchicalSoftmax: out[b, c*320 + t] = (x_b · topW[:,c] + top_b[c]) + (x_b · botW[t,:] + bot_b[t])
// B=1024, NHID=128, NCLASSES=320, PER_CLASS=320, row = 102400 fp32.
// Write-bound: 419.4 MB out -> floor ~67 us @ 6.3 TB/s (harness poison fills prove
// 6.2-6.4 TB/s for plain dwordx4 streaming stores).
//
// R1 -> R2 changes:
//  - drop nontemporal stores (match the 6.3 TB/s fill path)
//  - replace per-iter magic-div (c=g/80) with incremental (c,r) update
//  - strength-reduce store address to p += 256 (no per-iter 64-bit rebuild)

#define BATCH      1024
#define NHID       128
#define NCLASSES   320
#define PER_CLASS  320
#define ROW_ELEMS  (NCLASSES * PER_CLASS)   // 102400
#define ROW_F4     (ROW_ELEMS / 4)          // 25600
#define PC_F4      (PER_CLASS / 4)          // 80
#define NITER      (ROW_F4 / 256)           // 100 per thread

typedef float f32x4 __attribute__((ext_vector_type(4)));

__global__ __launch_bounds__(256) void hs_fused_kernel(
    const float* __restrict__ inputs,     // [B, NHID]
    const float* __restrict__ top_W,      // [NHID, NCLASSES]
    const float* __restrict__ top_b,      // [NCLASSES]
    const float* __restrict__ bottom_W,   // [PER_CLASS, NHID]
    const float* __restrict__ bottom_b,   // [NCLASSES]
    float* __restrict__ out)              // [B, ROW_ELEMS]
{
    __shared__ __align__(16) float s_in[NHID];
    __shared__ __align__(16) float s_top[NCLASSES];
    __shared__ __align__(16) float s_bot[PER_CLASS];

    const int b   = blockIdx.x;
    const int tid = threadIdx.x;

    // ---- Phase 0: stage input row in LDS ----
    if (tid < NHID) s_in[tid] = inputs[b * NHID + tid];
    __syncthreads();

    // ---- Phase 1: 320 top + 320 bottom logits for this row ----
    for (int j = tid; j < NCLASSES + PER_CLASS; j += 256) {
        float acc;
        if (j < NCLASSES) {
            acc = top_b[j];
            #pragma unroll 8
            for (int k = 0; k < NHID; ++k)
                acc += s_in[k] * top_W[k * NCLASSES + j];
            s_top[j] = acc;
        } else {
            const int t = j - NCLASSES;
            acc = bottom_b[t];
            const f32x4* w4 = (const f32x4*)(bottom_W + t * NHID);
            #pragma unroll 8
            for (int k4 = 0; k4 < NHID / 4; ++k4) {
                f32x4 w = w4[k4];
                acc += s_in[4 * k4 + 0] * w.x + s_in[4 * k4 + 1] * w.y
                     + s_in[4 * k4 + 2] * w.z + s_in[4 * k4 + 3] * w.w;
            }
            s_bot[t] = acc;
        }
    }
    __syncthreads();

    // ---- Phase 2: stream the row: out4[g] = top[g/80] + bot4[g%80], g = tid + 256*i ----
    // Incremental (c, r): g += 256 == c += 3, r += 16, with one borrow (256 = 3*80 + 16).
    f32x4* __restrict__ p = (f32x4*)(out + (size_t)b * ROW_ELEMS) + tid;
    const f32x4* __restrict__ bot4 = (const f32x4*)s_bot;

    int c = tid / PC_F4;          // 0..3 (tid < 256, PC_F4 = 80)
    int r = tid - c * PC_F4;      // 0..79

    #pragma unroll 4
    for (int i = 0; i < NITER; ++i) {
        const float tv = s_top[c];     // <=2 distinct addrs per wave: LDS broadcast, free
        f32x4 bv = bot4[r];            // 16B lane stride: conflict-free ds_read_b128
        f32x4 v;
        v.x = tv + bv.x;
        v.y = tv + bv.y;
        v.z = tv + bv.z;
        v.w = tv + bv.w;
        *p = v;                        // plain global_store_dwordx4 (fill-proven path)
        p += 256;
        // advance (c, r) for next g
        r += 16;
        const int wrap = (r >= PC_F4);
        c += 3 + wrap;
        r -= wrap ? PC_F4 : 0;
    }
}

extern "C" void kernel_launch(void* const* d_in, const int* in_sizes, int n_in,
                              void* d_out, int out_size, void* d_ws, size_t ws_size,
                              hipStream_t stream) {
    const float* inputs   = (const float*)d_in[0];
    const float* top_W    = (const float*)d_in[1];
    const float* top_b    = (const float*)d_in[2];
    const float* bottom_W = (const float*)d_in[3];
    const float* bottom_b = (const float*)d_in[4];
    float* out = (float*)d_out;

    hs_fused_kernel<<<BATCH, 256, 0, stream>>>(inputs, top_W, top_b, bottom_W, bottom_b, out);
}